// Round 1
// baseline (3463.971 us; speedup 1.0000x reference)
//
#include <hip/hip_runtime.h>
#include <math.h>

#define HW 16384
#define IMW 128

// ---------------- K0: zero the GAP accumulator (ws is poisoned each call) ----
__global__ void k0_zero(float* __restrict__ gap) {
    int i = blockIdx.x * 256 + threadIdx.x;
    if (i < 8 * 128) gap[i] = 0.f;
}

// ---------------- generic register-tiled GEMM over a 64-pixel tile ----------
// Output [M oc][64 px]; 256 threads = 16 oc-groups x 16 px-groups (4 px each).
// Acts come from LDS via actRow(k) -> row base pointer (stride-68 rows).
// Weights [M][K] row-major streamed global->LDS in K-chunks of 8.
template <int M, int MR, int K, class ARow, class Epi>
__device__ inline void gemm_tile(float* Wc, const float* __restrict__ Wg,
                                 ARow actRow, Epi epi, int tid) {
    constexpr int WS = M + 4;
    const int og = tid >> 4, pg = tid & 15;
    const int ocb = og * MR, pxb = pg * 4;
    float acc[MR][4];
#pragma unroll
    for (int m = 0; m < MR; m++)
#pragma unroll
        for (int j = 0; j < 4; j++) acc[m][j] = 0.f;

    for (int k0 = 0; k0 < K; k0 += 8) {
        // stage weight chunk transposed: Wc[kk][oc]
        for (int i = tid; i < 8 * M; i += 256) {
            int kk = i & 7, oc = i >> 3;
            Wc[kk * WS + oc] = Wg[oc * K + k0 + kk];
        }
        __syncthreads();
#pragma unroll
        for (int kk = 0; kk < 8; kk++) {
            const float* ar = actRow(k0 + kk);
            float4 av = *(const float4*)(ar + pxb);
            const float* wr = &Wc[kk * WS + ocb];
#pragma unroll
            for (int mq = 0; mq < MR / 4; mq++) {
                float4 w4 = *(const float4*)(wr + mq * 4);
                float wv[4] = {w4.x, w4.y, w4.z, w4.w};
#pragma unroll
                for (int mo = 0; mo < 4; mo++) {
                    int m = mq * 4 + mo;
                    acc[m][0] += wv[mo] * av.x;
                    acc[m][1] += wv[mo] * av.y;
                    acc[m][2] += wv[mo] * av.z;
                    acc[m][3] += wv[mo] * av.w;
                }
            }
        }
        __syncthreads();
    }
    epi(acc, ocb, pxb);
}

// ---------------- K1: t1 = relu(W1 @ concat(sx1,tx) + b1), GAP partial sums -
__global__ __launch_bounds__(256, 2) void k1_t1gap(
    const float* __restrict__ sx1, const float* __restrict__ tx,
    const float* __restrict__ t1_w, const float* __restrict__ t1_b,
    float* __restrict__ gap) {
    __shared__ __align__(16) float S[320 * 68];
    __shared__ __align__(16) float Wc[8 * 132];
    const int tid = threadIdx.x, bx = blockIdx.x;
    const int b = bx >> 8;
    const int p0 = (bx & 255) * 64;

    // stage acts: rows 0..255 = sx1 channels, rows 256..319 = tx channels
    for (int i = tid; i < 320 * 16; i += 256) {
        int row = i >> 4, q = i & 15;
        const float* src = (row < 256)
                               ? (sx1 + ((size_t)(b * 256 + row)) * HW + p0)
                               : (tx + ((size_t)(b * 64 + row - 256)) * HW + p0);
        *(float4*)(&S[row * 68 + q * 4]) = *(const float4*)(src + q * 4);
    }
    // (first __syncthreads inside gemm_tile makes these visible)

    gemm_tile<128, 8, 320>(
        Wc, t1_w, [&](int k) { return &S[k * 68]; },
        [&](float (*acc)[4], int ocb, int pxb) {
#pragma unroll
            for (int m = 0; m < 8; m++) {
                int oc = ocb + m;
                float bias = t1_b[oc];
                float s = 0.f;
#pragma unroll
                for (int j = 0; j < 4; j++) {
                    float v = acc[m][j] + bias;
                    s += (v > 0.f ? v : 0.f);
                }
                // reduce across the 16 px-groups (lane bits 0..3)
                s += __shfl_xor(s, 1);
                s += __shfl_xor(s, 2);
                s += __shfl_xor(s, 4);
                s += __shfl_xor(s, 8);
                if ((tid & 15) == 0) atomicAdd(&gap[b * 128 + oc], s);
            }
        },
        tid);
}

// ---------------- K2: GAP mean -> t2 -> t3 -> L2-normalize -> w -------------
__global__ __launch_bounds__(256) void k2_small(
    const float* __restrict__ gap, const float* __restrict__ t2_w,
    const float* __restrict__ t3_w, float* __restrict__ wn,
    float* __restrict__ wout) {
    __shared__ float w1[8 * 128];
    __shared__ float w2[8 * 64];
    __shared__ float w3[8 * 256];
    __shared__ float nrm[8];
    const int tid = threadIdx.x;
    for (int i = tid; i < 1024; i += 256) w1[i] = gap[i] * (1.f / 16384.f);
    __syncthreads();
    for (int i = tid; i < 512; i += 256) {
        int b = i >> 6, o = i & 63;
        float s = 0.f;
        for (int k = 0; k < 128; k++) s += t2_w[o * 128 + k] * w1[b * 128 + k];
        w2[i] = s > 0.f ? s : 0.f;
    }
    __syncthreads();
    for (int i = tid; i < 2048; i += 256) {
        int b = i >> 8, o = i & 255;
        float s = 0.f;
        for (int k = 0; k < 64; k++) s += t3_w[o * 64 + k] * w2[b * 64 + k];
        w3[i] = s;
    }
    __syncthreads();
    if (tid < 8) {
        float s = 0.f;
        for (int c = 0; c < 256; c++) {
            float v = w3[tid * 256 + c];
            s += v * v;
        }
        float n = sqrtf(s);
        nrm[tid] = n > 1e-12f ? n : 1e-12f;
    }
    __syncthreads();
    for (int i = tid; i < 2048; i += 256) {
        int b = i >> 8;
        float v = w3[i] / nrm[b];
        wn[i] = v;
        wout[i] = v;
    }
}

// ---------------- K3: fused chain U->scale->V->concat->a1->a2->gate -> g ----
__global__ __launch_bounds__(256, 2) void k3_chain(
    const float* __restrict__ sx2, const float* __restrict__ tx,
    const float* __restrict__ U_w, const float* __restrict__ U_b,
    const float* __restrict__ V_w, const float* __restrict__ V_b,
    const float* __restrict__ a1_w, const float* __restrict__ a1_b,
    const float* __restrict__ a2_w, const float* __restrict__ a2_b,
    const float* __restrict__ wn, float* __restrict__ gout) {
    __shared__ __align__(16) float bufA[256 * 68];  // sx2 -> {v rows0..127, tx rows128..191}
    __shared__ __align__(16) float bufB[256 * 68];  // u -> a1 (rows 0..127)
    __shared__ __align__(16) float Wc[8 * 260];
    const int tid = threadIdx.x, bx = blockIdx.x;
    const int b = bx >> 8;
    const int p0 = (bx & 255) * 64;

    // stage sx2 tile into bufA
    for (int i = tid; i < 256 * 16; i += 256) {
        int row = i >> 4, q = i & 15;
        *(float4*)(&bufA[row * 68 + q * 4]) =
            *(const float4*)(sx2 + ((size_t)(b * 256 + row)) * HW + p0 + q * 4);
    }

    // GEMM1: u = relu(U_w @ sx2 + U_b) * wn[b]  -> bufB
    gemm_tile<256, 16, 256>(
        Wc, U_w, [&](int k) { return &bufA[k * 68]; },
        [&](float (*acc)[4], int ocb, int pxb) {
#pragma unroll
            for (int m = 0; m < 16; m++) {
                int oc = ocb + m;
                float bias = U_b[oc];
                float sc = wn[b * 256 + oc];
#pragma unroll
                for (int j = 0; j < 4; j++) {
                    float v = acc[m][j] + bias;
                    v = v > 0.f ? v : 0.f;
                    bufB[oc * 68 + pxb + j] = v * sc;
                }
            }
        },
        tid);
    __syncthreads();

    // stage tx tile into bufA rows 128..191 (sx2 no longer needed)
    for (int i = tid; i < 64 * 16; i += 256) {
        int row = i >> 4, q = i & 15;
        *(float4*)(&bufA[(128 + row) * 68 + q * 4]) =
            *(const float4*)(tx + ((size_t)(b * 64 + row)) * HW + p0 + q * 4);
    }

    // GEMM2: v = relu(V_w @ u + V_b) -> bufA rows 0..127  (bvec = bufA rows 0..191)
    gemm_tile<128, 8, 256>(
        Wc, V_w, [&](int k) { return &bufB[k * 68]; },
        [&](float (*acc)[4], int ocb, int pxb) {
#pragma unroll
            for (int m = 0; m < 8; m++) {
                int oc = ocb + m;
                float bias = V_b[oc];
#pragma unroll
                for (int j = 0; j < 4; j++) {
                    float v = acc[m][j] + bias;
                    bufA[oc * 68 + pxb + j] = v > 0.f ? v : 0.f;
                }
            }
        },
        tid);
    __syncthreads();

    // GEMM3: a1 = relu(a1_w @ bvec + a1_b) -> bufB rows 0..127
    gemm_tile<128, 8, 192>(
        Wc, a1_w, [&](int k) { return &bufA[k * 68]; },
        [&](float (*acc)[4], int ocb, int pxb) {
#pragma unroll
            for (int m = 0; m < 8; m++) {
                int oc = ocb + m;
                float bias = a1_b[oc];
#pragma unroll
                for (int j = 0; j < 4; j++) {
                    float v = acc[m][j] + bias;
                    bufB[oc * 68 + pxb + j] = v > 0.f ? v : 0.f;
                }
            }
        },
        tid);
    __syncthreads();

    // GEMM4: g = sigmoid(a2_w @ a1 + a2_b) * bvec  -> global
    gemm_tile<192, 12, 128>(
        Wc, a2_w, [&](int k) { return &bufB[k * 68]; },
        [&](float (*acc)[4], int ocb, int pxb) {
#pragma unroll
            for (int m = 0; m < 12; m++) {
                int oc = ocb + m;
                float bias = a2_b[oc];
#pragma unroll
                for (int j = 0; j < 4; j++) {
                    float x = acc[m][j] + bias;
                    float sg = 1.f / (1.f + __expf(-x));
                    float bv = bufA[oc * 68 + pxb + j];
                    gout[((size_t)(b * 192 + oc)) * HW + p0 + pxb + j] = sg * bv;
                }
            }
        },
        tid);
}

// ---------------- K4: 3x3 conv, 256 oc x 128 px (one image row) per block ---
__global__ __launch_bounds__(256, 2) void k4_conv(
    const float* __restrict__ g, const float* __restrict__ ot_w,
    const float* __restrict__ ot_b, float* __restrict__ out) {
    __shared__ __align__(16) float Wl[36 * 260];      // 4 c x 9 taps x 256 oc
    __shared__ __align__(16) float Ac[4 * 3 * 132];   // 4 c x 3 rows x (128+halo)
    const int tid = threadIdx.x, bx = blockIdx.x;
    const int b = bx >> 7, h = bx & 127;
    const int og = tid >> 4, pg = tid & 15;
    const int ocb = og * 16, pxb = pg * 8;
    float acc[16][8];
#pragma unroll
    for (int m = 0; m < 16; m++)
#pragma unroll
        for (int j = 0; j < 8; j++) acc[m][j] = 0.f;

    for (int c0 = 0; c0 < 192; c0 += 4) {
        // stage acts with halo; Ac index x corresponds to w = x-1
        for (int i = tid; i < 4 * 3 * 132; i += 256) {
            int cc = i / 396, r = i % 396, dy = r / 132, x = r % 132;
            int hh = h + dy - 1;
            float v = 0.f;
            if (x >= 1 && x <= 128 && hh >= 0 && hh < 128)
                v = g[((size_t)(b * 192 + c0 + cc)) * HW + hh * IMW + (x - 1)];
            Ac[(cc * 3 + dy) * 132 + x] = v;
        }
        // stage weights: Wl[k][oc], k = cc*9 + dy*3 + dx
        for (int i = tid; i < 36 * 256; i += 256) {
            int oc = i / 36, k = i % 36;
            Wl[k * 260 + oc] = ot_w[(size_t)oc * 1728 + c0 * 9 + k];
        }
        __syncthreads();

        for (int cc = 0; cc < 4; cc++) {
            for (int dy = 0; dy < 3; dy++) {
                const float* ar = &Ac[(cc * 3 + dy) * 132 + pxb];
                float a[10];
                *(float4*)(&a[0]) = *(const float4*)(ar);
                *(float4*)(&a[4]) = *(const float4*)(ar + 4);
                a[8] = ar[8];
                a[9] = ar[9];
#pragma unroll
                for (int dx = 0; dx < 3; dx++) {
                    const float* wr = &Wl[(cc * 9 + dy * 3 + dx) * 260 + ocb];
#pragma unroll
                    for (int mq = 0; mq < 4; mq++) {
                        float4 w4 = *(const float4*)(wr + mq * 4);
                        float wv[4] = {w4.x, w4.y, w4.z, w4.w};
#pragma unroll
                        for (int mo = 0; mo < 4; mo++) {
                            int m = mq * 4 + mo;
#pragma unroll
                            for (int j = 0; j < 8; j++)
                                acc[m][j] += wv[mo] * a[j + dx];
                        }
                    }
                }
            }
        }
        __syncthreads();
    }
    // epilogue: bias + relu
#pragma unroll
    for (int m = 0; m < 16; m++) {
        int oc = ocb + m;
        float bias = ot_b[oc];
        float4 o0, o1;
        float t;
        t = acc[m][0] + bias; o0.x = t > 0.f ? t : 0.f;
        t = acc[m][1] + bias; o0.y = t > 0.f ? t : 0.f;
        t = acc[m][2] + bias; o0.z = t > 0.f ? t : 0.f;
        t = acc[m][3] + bias; o0.w = t > 0.f ? t : 0.f;
        t = acc[m][4] + bias; o1.x = t > 0.f ? t : 0.f;
        t = acc[m][5] + bias; o1.y = t > 0.f ? t : 0.f;
        t = acc[m][6] + bias; o1.z = t > 0.f ? t : 0.f;
        t = acc[m][7] + bias; o1.w = t > 0.f ? t : 0.f;
        float* dst = out + ((size_t)(b * 256 + oc)) * HW + h * IMW + pxb;
        *(float4*)(dst) = o0;
        *(float4*)(dst + 4) = o1;
    }
}

extern "C" void kernel_launch(void* const* d_in, const int* in_sizes, int n_in,
                              void* d_out, int out_size, void* d_ws,
                              size_t ws_size, hipStream_t stream) {
    const float* sx1 = (const float*)d_in[0];
    const float* sx2 = (const float*)d_in[1];
    const float* tx = (const float*)d_in[2];
    const float* t1_w = (const float*)d_in[3];
    const float* t1_b = (const float*)d_in[4];
    const float* t2_w = (const float*)d_in[5];
    const float* t3_w = (const float*)d_in[6];
    const float* U_w = (const float*)d_in[7];
    const float* U_b = (const float*)d_in[8];
    const float* V_w = (const float*)d_in[9];
    const float* V_b = (const float*)d_in[10];
    const float* a1_w = (const float*)d_in[11];
    const float* a1_b = (const float*)d_in[12];
    const float* a2_w = (const float*)d_in[13];
    const float* a2_b = (const float*)d_in[14];
    const float* ot_w = (const float*)d_in[15];
    const float* ot_b = (const float*)d_in[16];

    float* out = (float*)d_out;
    float* wout = out + 33554432;  // second output: w [8,256,1,1]

    float* g = (float*)d_ws;                                // [8][192][16384]
    float* gap = (float*)((char*)d_ws + 100663296);         // [8][128]
    float* wn = gap + 1024;                                 // [8][256]

    k0_zero<<<4, 256, 0, stream>>>(gap);
    k1_t1gap<<<2048, 256, 0, stream>>>(sx1, tx, t1_w, t1_b, gap);
    k2_small<<<1, 256, 0, stream>>>(gap, t2_w, t3_w, wn, wout);
    k3_chain<<<2048, 256, 0, stream>>>(sx2, tx, U_w, U_b, V_w, V_b, a1_w, a1_b,
                                       a2_w, a2_b, wn, g);
    k4_conv<<<1024, 256, 0, stream>>>(g, ot_w, ot_b, out);
}

// Round 2
// 719.878 us; speedup vs baseline: 4.8119x; 4.8119x over previous
//
#include <hip/hip_runtime.h>
#include <math.h>

#define HW 16384
#define IMW 128

typedef short short8 __attribute__((ext_vector_type(8)));
typedef short short4v __attribute__((ext_vector_type(4)));
typedef float f32x4 __attribute__((ext_vector_type(4)));

__device__ __forceinline__ short f2bf(float f) {
    unsigned u = __float_as_uint(f);
    u += 0x7FFFu + ((u >> 16) & 1u);
    return (short)(u >> 16);
}
__device__ __forceinline__ float bf2f(short h) {
    return __uint_as_float(((unsigned)(unsigned short)h) << 16);
}

// ---------------- k_prep: fp32->bf16 weights (+conv reorder), zero gap ------
// wAll layout (shorts): t1[128*320]@0, U[256*256]@40960, V[128*256]@106496,
//   a1[128*192]@139264, a2[192*128]@163840, conv[256*9*192]@188416
__global__ void k_prep(const float* __restrict__ t1_w, const float* __restrict__ U_w,
                       const float* __restrict__ V_w, const float* __restrict__ a1_w,
                       const float* __restrict__ a2_w, const float* __restrict__ ot_w,
                       short* __restrict__ wAll, float* __restrict__ gap) {
    int gid = blockIdx.x * 256 + threadIdx.x;
    int stride = gridDim.x * 256;
    for (int i = gid; i < 40960; i += stride) wAll[i] = f2bf(t1_w[i]);
    for (int i = gid; i < 65536; i += stride) wAll[40960 + i] = f2bf(U_w[i]);
    for (int i = gid; i < 32768; i += stride) wAll[106496 + i] = f2bf(V_w[i]);
    for (int i = gid; i < 24576; i += stride) wAll[139264 + i] = f2bf(a1_w[i]);
    for (int i = gid; i < 24576; i += stride) wAll[163840 + i] = f2bf(a2_w[i]);
    // conv: [oc][c][3][3] -> [oc][tap][c]
    for (int i = gid; i < 442368; i += stride) {
        int oc = i / 1728, r = i % 1728, t = r / 192, c = r % 192;
        wAll[188416 + i] = f2bf(ot_w[(oc * 192 + c) * 9 + t]);
    }
    for (int i = gid; i < 1024; i += stride) gap[i] = 0.f;
}

// ---------------- shared MFMA GEMM core -------------------------------------
// out[oc][px] = sum_k W[oc][k] * actT[px][k]; block = [M oc] x [128 px],
// 512 thr = 8 waves = 4 ocg x 2 pxg; wave tile = TO oc-tiles x 4 px-tiles.
// actT in LDS: bf16 [px][K], row stride SB bytes, XOR-swizzled by (px&7)<<4.
// W staged per 32-k chunk into Wc[oc][40] (pad row to 80B for bank spread).
template <int MT, int KC, int TO, int SB>
__device__ __forceinline__ void run_gemm(const short* __restrict__ Wg,
                                         const char* __restrict__ bIn,
                                         short* __restrict__ Wc, f32x4 (*acc)[4],
                                         int tid, int l15, int g, int ocg, int pxg) {
#pragma unroll
    for (int t = 0; t < TO; t++)
#pragma unroll
        for (int p = 0; p < 4; p++) acc[t][p] = (f32x4){0.f, 0.f, 0.f, 0.f};
    for (int kc = 0; kc < KC; kc++) {
        __syncthreads();
        for (int i = tid; i < MT * 4; i += 512) {
            int oc = i >> 2, q = i & 3;
            *(short8*)(&Wc[oc * 40 + q * 8]) =
                *(const short8*)(Wg + oc * (KC * 32) + kc * 32 + q * 8);
        }
        __syncthreads();
        short8 a[TO];
#pragma unroll
        for (int t = 0; t < TO; t++)
            a[t] = *(const short8*)(&Wc[((ocg * TO + t) * 16 + l15) * 40 + g * 8]);
#pragma unroll
        for (int p = 0; p < 4; p++) {
            int px = (pxg * 4 + p) * 16 + l15;
            short8 bfr = *(const short8*)(
                bIn + ((px * SB + kc * 64 + g * 16) ^ ((px & 7) << 4)));
#pragma unroll
            for (int t = 0; t < TO; t++)
                acc[t][p] =
                    __builtin_amdgcn_mfma_f32_16x16x32_bf16(a[t], bfr, acc[t][p], 0, 0, 0);
        }
    }
}

// ---------------- K1: t1 = relu(W1 @ concat(sx1,tx) + b1) -> GAP sums -------
__global__ __launch_bounds__(512, 2) void k1_t1gap(
    const float* __restrict__ sx1, const float* __restrict__ tx,
    const short* __restrict__ wt1, const float* __restrict__ t1_b,
    float* __restrict__ gap) {
    __shared__ __align__(16) char bufA[128 * 640];  // [128px][320c] bf16, swizzled
    __shared__ __align__(16) short Wc[128 * 40];
    const int tid = threadIdx.x;
    const int b = blockIdx.x >> 7;
    const int p0 = (blockIdx.x & 127) * 128;
    const int lane = tid & 63, wid = tid >> 6;
    const int ocg = wid >> 1, pxg = wid & 1;
    const int l15 = lane & 15, g = lane >> 4;

    // stage concat(sx1,tx) transposed
    for (int i = tid; i < 80 * 32; i += 512) {
        int cg = i % 80, pg = i / 80;
        int c4 = cg * 4, px4 = pg * 4;
        f32x4 v[4];
#pragma unroll
        for (int cc = 0; cc < 4; cc++) {
            int row = c4 + cc;
            const float* src = (row < 256)
                                   ? (sx1 + ((size_t)(b * 256 + row)) * HW + p0 + px4)
                                   : (tx + ((size_t)(b * 64 + row - 256)) * HW + p0 + px4);
            v[cc] = *(const f32x4*)src;
        }
#pragma unroll
        for (int j = 0; j < 4; j++) {
            short4v s = {f2bf(v[0][j]), f2bf(v[1][j]), f2bf(v[2][j]), f2bf(v[3][j])};
            int px = px4 + j;
            *(short4v*)(bufA + ((px * 640 + c4 * 2) ^ ((px & 7) << 4))) = s;
        }
    }
    f32x4 acc[2][4];
    run_gemm<128, 10, 2, 640>(wt1, bufA, Wc, acc, tid, l15, g, ocg, pxg);
    // epilogue: relu + per-block GAP partial sum -> atomicAdd
#pragma unroll
    for (int t = 0; t < 2; t++) {
        int oc0 = (ocg * 2 + t) * 16 + g * 4;
        float s[4];
#pragma unroll
        for (int r = 0; r < 4; r++) {
            float bias = t1_b[oc0 + r];
            float accv = 0.f;
#pragma unroll
            for (int p = 0; p < 4; p++) {
                float v = acc[t][p][r] + bias;
                accv += (v > 0.f ? v : 0.f);
            }
            s[r] = accv;
        }
#pragma unroll
        for (int r = 0; r < 4; r++) {
            s[r] += __shfl_xor(s[r], 1);
            s[r] += __shfl_xor(s[r], 2);
            s[r] += __shfl_xor(s[r], 4);
            s[r] += __shfl_xor(s[r], 8);
        }
        if (l15 == 0)
#pragma unroll
            for (int r = 0; r < 4; r++) atomicAdd(&gap[b * 128 + oc0 + r], s[r]);
    }
}

// ---------------- K2: GAP mean -> t2 -> t3 -> L2 normalize ------------------
__global__ __launch_bounds__(256) void k2_small(
    const float* __restrict__ gap, const float* __restrict__ t2_w,
    const float* __restrict__ t3_w, float* __restrict__ wn, float* __restrict__ wout) {
    __shared__ float w1[8 * 128];
    __shared__ float w2[8 * 64];
    __shared__ float w3[8 * 256];
    __shared__ float nrm[8];
    const int tid = threadIdx.x;
    for (int i = tid; i < 1024; i += 256) w1[i] = gap[i] * (1.f / 16384.f);
    __syncthreads();
    for (int i = tid; i < 512; i += 256) {
        int b = i >> 6, o = i & 63;
        float s = 0.f;
        for (int k = 0; k < 128; k++) s += t2_w[o * 128 + k] * w1[b * 128 + k];
        w2[i] = s > 0.f ? s : 0.f;
    }
    __syncthreads();
    for (int i = tid; i < 2048; i += 256) {
        int b = i >> 8, o = i & 255;
        float s = 0.f;
        for (int k = 0; k < 64; k++) s += t3_w[o * 64 + k] * w2[b * 64 + k];
        w3[i] = s;
    }
    __syncthreads();
    if (tid < 8) {
        float s = 0.f;
        for (int c = 0; c < 256; c++) {
            float v = w3[tid * 256 + c];
            s += v * v;
        }
        float n = sqrtf(s);
        nrm[tid] = n > 1e-12f ? n : 1e-12f;
    }
    __syncthreads();
    for (int i = tid; i < 2048; i += 256) {
        int b = i >> 8;
        float v = w3[i] / nrm[b];
        wn[i] = v;
        wout[i] = v;
    }
}

// ---------------- K3: fused U->scale->V->concat->a1->a2->gate -> g ----------
// g2 layout: bf16 [b][chunk=c/32][hw][32]
__global__ __launch_bounds__(512, 2) void k3_chain(
    const float* __restrict__ sx2, const float* __restrict__ tx,
    const short* __restrict__ wU, const float* __restrict__ U_b,
    const short* __restrict__ wV, const float* __restrict__ V_b,
    const short* __restrict__ wa1, const float* __restrict__ a1_b,
    const short* __restrict__ wa2, const float* __restrict__ a2_b,
    const float* __restrict__ wn, short* __restrict__ g2) {
    __shared__ __align__(16) char bufA[128 * 512];  // [128px][256c] bf16 swizzled
    __shared__ __align__(16) char bufB[128 * 512];
    __shared__ __align__(16) short Wc[256 * 40];
    const int tid = threadIdx.x;
    const int b = blockIdx.x >> 7;
    const int p0 = (blockIdx.x & 127) * 128;
    const int lane = tid & 63, wid = tid >> 6;
    const int ocg = wid >> 1, pxg = wid & 1;
    const int l15 = lane & 15, g = lane >> 4;
    f32x4 acc[4][4];

    // stage sx2 -> bufA
    for (int i = tid; i < 64 * 32; i += 512) {
        int cg = i & 63, pg = i >> 6;
        int c4 = cg * 4, px4 = pg * 4;
        f32x4 v[4];
#pragma unroll
        for (int cc = 0; cc < 4; cc++)
            v[cc] = *(const f32x4*)(sx2 + ((size_t)(b * 256 + c4 + cc)) * HW + p0 + px4);
#pragma unroll
        for (int j = 0; j < 4; j++) {
            short4v s = {f2bf(v[0][j]), f2bf(v[1][j]), f2bf(v[2][j]), f2bf(v[3][j])};
            int px = px4 + j;
            *(short4v*)(bufA + ((px * 512 + c4 * 2) ^ ((px & 7) << 4))) = s;
        }
    }

    // GEMM1: u = relu(U@sx2 + Ub) * wn  -> bufB
    run_gemm<256, 8, 4, 512>(wU, bufA, Wc, acc, tid, l15, g, ocg, pxg);
#pragma unroll
    for (int t = 0; t < 4; t++) {
        int oc0 = (ocg * 4 + t) * 16 + g * 4;
        float bi[4], sc[4];
#pragma unroll
        for (int r = 0; r < 4; r++) {
            bi[r] = U_b[oc0 + r];
            sc[r] = wn[b * 256 + oc0 + r];
        }
#pragma unroll
        for (int p = 0; p < 4; p++) {
            int px = (pxg * 4 + p) * 16 + l15;
            short4v s;
#pragma unroll
            for (int r = 0; r < 4; r++) {
                float v = acc[t][p][r] + bi[r];
                v = v > 0.f ? v : 0.f;
                s[r] = f2bf(v * sc[r]);
            }
            *(short4v*)(bufB + ((px * 512 + oc0 * 2) ^ ((px & 7) << 4))) = s;
        }
    }
    __syncthreads();  // all waves done reading bufA (GEMM1)
    // stage tx -> bufA cols 128..191
    {
        int cg = tid & 15, pg = tid >> 4;
        int c4 = cg * 4, px4 = pg * 4;
        f32x4 v[4];
#pragma unroll
        for (int cc = 0; cc < 4; cc++)
            v[cc] = *(const f32x4*)(tx + ((size_t)(b * 64 + c4 + cc)) * HW + p0 + px4);
#pragma unroll
        for (int j = 0; j < 4; j++) {
            short4v s = {f2bf(v[0][j]), f2bf(v[1][j]), f2bf(v[2][j]), f2bf(v[3][j])};
            int px = px4 + j;
            *(short4v*)(bufA + ((px * 512 + (128 + c4) * 2) ^ ((px & 7) << 4))) = s;
        }
    }

    // GEMM2: v = relu(V@u + Vb) -> bufA cols 0..127
    run_gemm<128, 8, 2, 512>(wV, bufB, Wc, acc, tid, l15, g, ocg, pxg);
#pragma unroll
    for (int t = 0; t < 2; t++) {
        int oc0 = (ocg * 2 + t) * 16 + g * 4;
        float bi[4];
#pragma unroll
        for (int r = 0; r < 4; r++) bi[r] = V_b[oc0 + r];
#pragma unroll
        for (int p = 0; p < 4; p++) {
            int px = (pxg * 4 + p) * 16 + l15;
            short4v s;
#pragma unroll
            for (int r = 0; r < 4; r++) {
                float v = acc[t][p][r] + bi[r];
                s[r] = f2bf(v > 0.f ? v : 0.f);
            }
            *(short4v*)(bufA + ((px * 512 + oc0 * 2) ^ ((px & 7) << 4))) = s;
        }
    }

    // GEMM3: a1 = relu(a1w@bvec + a1b) -> bufB cols 0..127  (bvec = bufA[0..191])
    run_gemm<128, 6, 2, 512>(wa1, bufA, Wc, acc, tid, l15, g, ocg, pxg);
#pragma unroll
    for (int t = 0; t < 2; t++) {
        int oc0 = (ocg * 2 + t) * 16 + g * 4;
        float bi[4];
#pragma unroll
        for (int r = 0; r < 4; r++) bi[r] = a1_b[oc0 + r];
#pragma unroll
        for (int p = 0; p < 4; p++) {
            int px = (pxg * 4 + p) * 16 + l15;
            short4v s;
#pragma unroll
            for (int r = 0; r < 4; r++) {
                float v = acc[t][p][r] + bi[r];
                s[r] = f2bf(v > 0.f ? v : 0.f);
            }
            *(short4v*)(bufB + ((px * 512 + oc0 * 2) ^ ((px & 7) << 4))) = s;
        }
    }

    // GEMM4: g = sigmoid(a2w@a1 + a2b) * bvec -> g2 global
    run_gemm<192, 4, 3, 512>(wa2, bufB, Wc, acc, tid, l15, g, ocg, pxg);
#pragma unroll
    for (int t = 0; t < 3; t++) {
        int oc0 = (ocg * 3 + t) * 16 + g * 4;
        float bi[4];
#pragma unroll
        for (int r = 0; r < 4; r++) bi[r] = a2_b[oc0 + r];
        int chunk = oc0 >> 5, co = oc0 & 31;
#pragma unroll
        for (int p = 0; p < 4; p++) {
            int px = (pxg * 4 + p) * 16 + l15;
            short4v bv = *(const short4v*)(bufA + ((px * 512 + oc0 * 2) ^ ((px & 7) << 4)));
            short4v s;
#pragma unroll
            for (int r = 0; r < 4; r++) {
                float x = acc[t][p][r] + bi[r];
                float sg = 1.f / (1.f + __expf(-x));
                s[r] = f2bf(sg * bf2f(bv[r]));
            }
            *(short4v*)(g2 + (((size_t)(b * 6 + chunk)) * HW + (p0 + px)) * 32 + co) = s;
        }
    }
}

// ---------------- K4: 3x3 conv as 9 shifted MFMA GEMMs ----------------------
// block: 256 oc x 256 px (2 image rows); 8 waves = 4 ocg x 2 pxg(row);
// wave tile = 4 oc-tiles x 8 px-tiles.
__global__ __launch_bounds__(512, 2) void k4_conv(
    const short* __restrict__ g2, const short* __restrict__ wconv,
    const float* __restrict__ ot_b, float* __restrict__ out) {
    __shared__ __align__(16) short Wg[3 * 256 * 40];    // taps (dy,0..2): [tg][oc][40]
    __shared__ __align__(16) short actT[4 * 132 * 40];  // [ri][x][c-chunk 32 pad40]
    const int tid = threadIdx.x;
    const int b = blockIdx.x >> 6;
    const int h0 = (blockIdx.x & 63) * 2;
    const int lane = tid & 63, wid = tid >> 6;
    const int ocg = wid >> 1, pxg = wid & 1;
    const int l15 = lane & 15, g = lane >> 4;
    f32x4 acc[4][8];
#pragma unroll
    for (int t = 0; t < 4; t++)
#pragma unroll
        for (int p = 0; p < 8; p++) acc[t][p] = (f32x4){0.f, 0.f, 0.f, 0.f};

    for (int cc = 0; cc < 6; cc++) {
        __syncthreads();
        // stage acts: rows h0-1..h0+2, x_img -1..130, 32 channels
        for (int i = tid; i < 2112; i += 512) {
            int ri = i / 528, rem = i % 528, x = rem >> 2, q = rem & 3;
            int hh = h0 - 1 + ri, xx = x - 1;
            short8 v = {0, 0, 0, 0, 0, 0, 0, 0};
            if (hh >= 0 && hh < 128 && xx >= 0 && xx < 128)
                v = *(const short8*)(
                    g2 + (((size_t)(b * 6 + cc)) * HW + hh * IMW + xx) * 32 + q * 8);
            *(short8*)(&actT[(ri * 132 + x) * 40 + q * 8]) = v;
        }
        for (int dy = 0; dy < 3; dy++) {
            if (dy > 0) __syncthreads();  // protect Wg from previous taps' readers
            for (int i = tid; i < 3072; i += 512) {
                int tg = i >> 10, r = i & 1023, oc = r >> 2, q = r & 3;
                *(short8*)(&Wg[(tg * 256 + oc) * 40 + q * 8]) = *(const short8*)(
                    wconv + (size_t)oc * 1728 + (dy * 3 + tg) * 192 + cc * 32 + q * 8);
            }
            __syncthreads();
#pragma unroll
            for (int dx = 0; dx < 3; dx++) {
                short8 a[4];
#pragma unroll
                for (int t = 0; t < 4; t++)
                    a[t] = *(const short8*)(
                        &Wg[(dx * 256 + (ocg * 4 + t) * 16 + l15) * 40 + g * 8]);
                int ri = pxg + dy;
#pragma unroll
                for (int p = 0; p < 8; p++) {
                    int x = p * 16 + l15 + dx;
                    short8 bf = *(const short8*)(&actT[(ri * 132 + x) * 40 + g * 8]);
#pragma unroll
                    for (int t = 0; t < 4; t++)
                        acc[t][p] =
                            __builtin_amdgcn_mfma_f32_16x16x32_bf16(a[t], bf, acc[t][p], 0, 0, 0);
                }
            }
        }
    }
    // epilogue: bias + relu -> out fp32
    const int h = h0 + pxg;
#pragma unroll
    for (int t = 0; t < 4; t++) {
        int oc0 = (ocg * 4 + t) * 16 + g * 4;
#pragma unroll
        for (int r = 0; r < 4; r++) {
            int oc = oc0 + r;
            float bias = ot_b[oc];
            float* dst = out + ((size_t)(b * 256 + oc)) * HW + h * IMW;
#pragma unroll
            for (int p = 0; p < 8; p++) {
                int x = p * 16 + l15;
                float v = acc[t][p][r] + bias;
                dst[x] = v > 0.f ? v : 0.f;
            }
        }
    }
}

extern "C" void kernel_launch(void* const* d_in, const int* in_sizes, int n_in,
                              void* d_out, int out_size, void* d_ws, size_t ws_size,
                              hipStream_t stream) {
    const float* sx1 = (const float*)d_in[0];
    const float* sx2 = (const float*)d_in[1];
    const float* tx = (const float*)d_in[2];
    const float* t1_w = (const float*)d_in[3];
    const float* t1_b = (const float*)d_in[4];
    const float* t2_w = (const float*)d_in[5];
    const float* t3_w = (const float*)d_in[6];
    const float* U_w = (const float*)d_in[7];
    const float* U_b = (const float*)d_in[8];
    const float* V_w = (const float*)d_in[9];
    const float* V_b = (const float*)d_in[10];
    const float* a1_w = (const float*)d_in[11];
    const float* a1_b = (const float*)d_in[12];
    const float* a2_w = (const float*)d_in[13];
    const float* a2_b = (const float*)d_in[14];
    const float* ot_w = (const float*)d_in[15];
    const float* ot_b = (const float*)d_in[16];

    float* out = (float*)d_out;
    float* wout = out + 33554432;  // output 1: w [8,256,1,1]

    short* g2 = (short*)d_ws;                                  // bf16 [8][6][HW][32]
    short* wAll = (short*)((char*)d_ws + 50331648);            // bf16 weights
    float* gap = (float*)((char*)d_ws + 51593216);             // [8][128]
    float* wn = (float*)((char*)d_ws + 51597312);              // [8][256]

    const short* wt1 = wAll;
    const short* wU = wAll + 40960;
    const short* wV = wAll + 106496;
    const short* wa1 = wAll + 139264;
    const short* wa2 = wAll + 163840;
    const short* wcv = wAll + 188416;

    k_prep<<<512, 256, 0, stream>>>(t1_w, U_w, V_w, a1_w, a2_w, ot_w, wAll, gap);
    k1_t1gap<<<1024, 512, 0, stream>>>(sx1, tx, wt1, t1_b, gap);
    k2_small<<<1, 256, 0, stream>>>(gap, t2_w, t3_w, wn, wout);
    k3_chain<<<1024, 512, 0, stream>>>(sx2, tx, wU, U_b, wV, V_b, wa1, a1_b, wa2,
                                       a2_b, wn, g2);
    k4_conv<<<512, 512, 0, stream>>>(g2, wcv, ot_b, out);
}